// Round 2
// baseline (167.164 us; speedup 1.0000x reference)
//
#include <hip/hip_runtime.h>
#include <math.h>

#define Hh 72
#define Ww 128
#define HW (Hh*Ww)          // 9216 grid points
#define NP 24               // points per curve
#define Mp 40               // pred curves
#define Ng 24               // gt curves
#define Bb 2                // batch
#define NRS 64
#define THICKc 0.03f
#define SHARPc 80.0f
#define NSUM (Bb*(Mp+Ng))   // 128 per-curve mask-sum accumulators

// ---------------------------------------------------------------------------
// K1: prepare gt mask + arclength resample (both pred and gt) to NRS points.
// One block per curve, 64 threads (one per resample point).
// Also zero-inits the per-curve mask-sum accumulators (ws is 0xAA-poisoned).
// ---------------------------------------------------------------------------
__global__ __launch_bounds__(64) void k_resample(
    const float* __restrict__ pred,   // B*M*NP*2
    const float* __restrict__ gt,     // B*N*NP*2
    const float* __restrict__ vis,    // B*N*NP
    float* __restrict__ predRS,       // B*M*NRS*2
    float* __restrict__ gtRS,         // B*N*NRS*2
    float* __restrict__ gtPM,         // B*N*NP
    float* __restrict__ maskSum)      // NSUM
{
    int blk = blockIdx.x;             // 0 .. B*(M+N)-1
    int b = blk / (Mp + Ng);
    int c = blk % (Mp + Ng);
    bool isPred = (c < Mp);
    int tid = threadIdx.x;

    if (tid == 0) maskSum[blk] = 0.0f;   // one accumulator per block, exact match

    __shared__ float qx[NP], qy[NP], pm[NP], cum[NP];
    __shared__ float s_total;

    const float* src = isPred ? pred + (size_t)(b * Mp + c) * NP * 2
                              : gt   + (size_t)(b * Ng + (c - Mp)) * NP * 2;
    if (tid < NP) {
        qx[tid] = src[tid * 2 + 0];
        qy[tid] = src[tid * 2 + 1];
        pm[tid] = isPred ? 1.0f
                         : ((vis[(b * Ng + (c - Mp)) * NP + tid] > 0.5f) ? 1.0f : 0.0f);
    }
    __syncthreads();
    if (tid == 0) {
        if (!isPred) {
            float s = 0.0f;
            for (int p = 0; p < NP; p++) s += pm[p];
            if (s < 2.0f)                       // fallback: fewer than 2 visible
                for (int p = 0; p < NP; p++) pm[p] = 1.0f;
        }
        float acc = 0.0f;
        cum[0] = 0.0f;
        for (int s = 0; s < NP - 1; s++) {
            float dx = qx[s + 1] - qx[s], dy = qy[s + 1] - qy[s];
            float sl = sqrtf(dx * dx + dy * dy) * (pm[s] * pm[s + 1]);
            acc += sl;
            cum[s + 1] = acc;
        }
        s_total = acc;
    }
    __syncthreads();
    if (!isPred && tid < NP) gtPM[(b * Ng + (c - Mp)) * NP + tid] = pm[tid];

    float total = s_total;
    float t = ((float)tid / 63.0f) * total;
    // searchsorted(cum, t, side='right') - 1  == count(cum <= t) - 1
    int cnt = 0;
    for (int p = 0; p < NP; p++) cnt += (cum[p] <= t) ? 1 : 0;
    int idx = cnt - 1;
    idx = (idx < 0) ? 0 : ((idx > NP - 2) ? NP - 2 : idx);
    float lt = cum[idx], rt = cum[idx + 1];
    float alpha = (t - lt) / fmaxf(rt - lt, 1e-8f);
    float ox = qx[idx] + alpha * (qx[idx + 1] - qx[idx]);
    float oy = qy[idx] + alpha * (qy[idx + 1] - qy[idx]);
    if (total < 1e-8f) { ox = qx[0]; oy = qy[0]; }   // degenerate curve
    float* dst = isPred ? predRS + (size_t)(b * Mp + c) * NRS * 2
                        : gtRS   + (size_t)(b * Ng + (c - Mp)) * NRS * 2;
    dst[tid * 2 + 0] = ox;
    dst[tid * 2 + 1] = oy;
}

// ---------------------------------------------------------------------------
// K2: soft occupancy masks on the ORIGINAL 24-pt polylines + per-curve sums.
// grid = (HW/256, B*(M+N)); block handles 256 grid points of one curve.
// ---------------------------------------------------------------------------
__global__ __launch_bounds__(256) void k_softmask(
    const float* __restrict__ pred,
    const float* __restrict__ gt,
    const float* __restrict__ gtPM,
    float* __restrict__ pmask,        // B*M*HW
    float* __restrict__ gmask,        // B*N*HW
    float* __restrict__ maskSum)      // NSUM: [0,80)=pred, [80,128)=gt
{
    int c = blockIdx.y;               // 0 .. B*(M+N)-1
    int b = c / (Mp + Ng);
    int cc = c % (Mp + Ng);
    bool isPred = (cc < Mp);
    int g = blockIdx.x * blockDim.x + threadIdx.x;

    __shared__ float qx[NP], qy[NP], pm[NP];
    if (threadIdx.x < NP) {
        const float* src = isPred ? pred + (size_t)(b * Mp + cc) * NP * 2
                                  : gt   + (size_t)(b * Ng + (cc - Mp)) * NP * 2;
        qx[threadIdx.x] = src[threadIdx.x * 2 + 0];
        qy[threadIdx.x] = src[threadIdx.x * 2 + 1];
        pm[threadIdx.x] = isPred ? 1.0f : gtPM[(b * Ng + (cc - Mp)) * NP + threadIdx.x];
    }
    __syncthreads();

    float gx = (float)(g & (Ww - 1)) * (1.0f / 127.0f);
    float gy = (float)(g >> 7) * (1.0f / 71.0f);

    float best2 = 1e30f;
    bool anyValid = false;
    for (int s = 0; s < NP - 1; s++) {
        if (pm[s] * pm[s + 1] > 0.5f) {          // wave-uniform branch (pm is per-curve)
            anyValid = true;
            float ax = qx[s], ay = qy[s];
            float abx = qx[s + 1] - ax, aby = qy[s + 1] - ay;
            float denom = fmaxf(abx * abx + aby * aby, 1e-8f);
            float t = ((gx - ax) * abx + (gy - ay) * aby) / denom;
            t = fminf(fmaxf(t, 0.0f), 1.0f);
            float dx = gx - (ax + t * abx), dy = gy - (ay + t * aby);
            best2 = fminf(best2, dx * dx + dy * dy);
        }
    }
    float mind;
    if (anyValid) {
        mind = sqrtf(best2);
    } else {
        float b2 = 1e30f;
        for (int p = 0; p < NP; p++) {
            if (pm[p] > 0.5f) {
                float dx = gx - qx[p], dy = gy - qy[p];
                b2 = fminf(b2, dx * dx + dy * dy);
            }
        }
        mind = sqrtf(b2);
    }
    float x = (THICKc - mind) * SHARPc;
    float mval = 1.0f / (1.0f + __expf(-x));
    int sumIdx;
    if (isPred) {
        pmask[(size_t)(b * Mp + cc) * HW + g] = mval;
        sumIdx = b * Mp + cc;
    } else {
        gmask[(size_t)(b * Ng + (cc - Mp)) * HW + g] = mval;
        sumIdx = Bb * Mp + b * Ng + (cc - Mp);
    }
    // per-wave shuffle reduce then one atomic per wave (4 per block)
    float ws = mval;
    for (int off = 32; off > 0; off >>= 1) ws += __shfl_down(ws, off);
    if ((threadIdx.x & 63) == 0) atomicAdd(&maskSum[sumIdx], ws);
}

// ---------------------------------------------------------------------------
// K3: per-(b,i,j) pair cost. 256 threads: all do the intersection grid sum
// (float4, 9 iters); wave 0 does Chamfer/tangent/curvature. One barrier.
// Union = Sp + Sq - inter (min+max == p+q identity).
// ---------------------------------------------------------------------------
__global__ __launch_bounds__(256) void k_cost(
    const float* __restrict__ predRS,
    const float* __restrict__ gtRS,
    const float* __restrict__ pmask,
    const float* __restrict__ gmask,
    const float* __restrict__ maskSum,
    const float* __restrict__ gtExist,   // B*N
    float* __restrict__ out)             // B*M*N
{
    int pair = blockIdx.x;               // B*M*N
    int j = pair % Ng;
    int i = (pair / Ng) % Mp;
    int b = pair / (Ng * Mp);
    int tid = threadIdx.x;
    int lane = tid & 63, wid = tid >> 6;

    __shared__ float px[NRS], py[NRS], gxr[NRS], gyr[NRS];
    __shared__ float partial[4];

    if (tid < NRS) {
        px[tid]  = predRS[((size_t)(b * Mp + i) * NRS + tid) * 2 + 0];
        py[tid]  = predRS[((size_t)(b * Mp + i) * NRS + tid) * 2 + 1];
        gxr[tid] = gtRS[((size_t)(b * Ng + j) * NRS + tid) * 2 + 0];
        gyr[tid] = gtRS[((size_t)(b * Ng + j) * NRS + tid) * 2 + 1];
    }
    __syncthreads();

    // ---- intersection: sum of min over the 9216-pt grid, float4 ----
    const float4* pm4 = (const float4*)(pmask + (size_t)(b * Mp + i) * HW);
    const float4* gm4 = (const float4*)(gmask + (size_t)(b * Ng + j) * HW);
    float smin = 0.0f;
    for (int g = tid; g < HW / 4; g += 256) {
        float4 p = pm4[g], q = gm4[g];
        smin += fminf(p.x, q.x) + fminf(p.y, q.y) + fminf(p.z, q.z) + fminf(p.w, q.w);
    }

    float symv = 0.0f, tanv = 0.0f, curvv = 0.0f;
    if (wid == 0) {
        // Chamfer: pred point tid -> gt polyline
        float p0x = px[lane], p0y = py[lane];
        float bst = 1e30f;
        for (int s = 0; s < NRS - 1; s++) {
            float ax = gxr[s], ay = gyr[s];
            float abx = gxr[s + 1] - ax, aby = gyr[s + 1] - ay;
            float denom = fmaxf(abx * abx + aby * aby, 1e-8f);
            float t = ((p0x - ax) * abx + (p0y - ay) * aby) / denom;
            t = fminf(fmaxf(t, 0.0f), 1.0f);
            float dx = p0x - (ax + t * abx), dy = p0y - (ay + t * aby);
            bst = fminf(bst, dx * dx + dy * dy);
        }
        float dpg = sqrtf(bst);
        // gt point tid -> pred polyline
        float q0x = gxr[lane], q0y = gyr[lane];
        bst = 1e30f;
        for (int s = 0; s < NRS - 1; s++) {
            float ax = px[s], ay = py[s];
            float abx = px[s + 1] - ax, aby = py[s + 1] - ay;
            float denom = fmaxf(abx * abx + aby * aby, 1e-8f);
            float t = ((q0x - ax) * abx + (q0y - ay) * aby) / denom;
            t = fminf(fmaxf(t, 0.0f), 1.0f);
            float dx = q0x - (ax + t * abx), dy = q0y - (ay + t * aby);
            bst = fminf(bst, dx * dx + dy * dy);
        }
        float dgp = sqrtf(bst);
        symv = 0.5f * (dpg + dgp);

        // tangent alignment
        int kp = (lane == NRS - 1) ? NRS - 1 : lane + 1;
        int km = (lane == 0) ? 0 : lane - 1;
        float tx = px[kp] - px[km], ty = py[kp] - py[km];
        float nrm = fmaxf(sqrtf(tx * tx + ty * ty), 1e-8f);
        tx /= nrm; ty /= nrm;
        float gtx = gxr[kp] - gxr[km], gty = gyr[kp] - gyr[km];
        float nrm2 = fmaxf(sqrtf(gtx * gtx + gty * gty), 1e-8f);
        gtx /= nrm2; gty /= nrm2;
        tanv = fabsf(tx * gtx + ty * gty);

        // curvature (second differences), lanes 0..61
        if (lane < NRS - 2) {
            float psx = px[lane + 2] - 2.0f * px[lane + 1] + px[lane];
            float psy = py[lane + 2] - 2.0f * py[lane + 1] + py[lane];
            float gsx = gxr[lane + 2] - 2.0f * gxr[lane + 1] + gxr[lane];
            float gsy = gyr[lane + 2] - 2.0f * gyr[lane + 1] + gyr[lane];
            float d1 = fabsf(psx - gsx);
            float d2 = fabsf(psy - gsy);
            float c1 = (d1 < 1.0f) ? 0.5f * d1 * d1 : d1 - 0.5f;
            float c2 = (d2 < 1.0f) ? 0.5f * d2 * d2 : d2 - 0.5f;
            curvv = c1 + c2;
        }
    }

    // per-wave reduce smin (all 4 waves); wave 0 also reduces curve terms
    for (int off = 32; off > 0; off >>= 1) smin += __shfl_down(smin, off);
    if (lane == 0) partial[wid] = smin;
    if (wid == 0) {
        for (int off = 32; off > 0; off >>= 1) {
            symv  += __shfl_down(symv,  off);
            tanv  += __shfl_down(tanv,  off);
            curvv += __shfl_down(curvv, off);
        }
    }
    __syncthreads();

    if (tid == 0) {
        float Smin = partial[0] + partial[1] + partial[2] + partial[3];
        float Sp = maskSum[b * Mp + i];
        float Sq = maskSum[Bb * Mp + b * Ng + j];
        float Smax = Sp + Sq - Smin;          // min+max == p+q
        float overlap = 1.0f - Smin / (Smax + 1e-8f);
        float sym  = symv * (1.0f / 64.0f);
        float tanl = 1.0f - tanv * (1.0f / 64.0f);
        float curv = curvv * (1.0f / 124.0f);
        float cost = 5.0f * sym + 1.0f * tanl + 0.5f * curv + 2.0f * overlap;
        float e = (gtExist[b * Ng + j] > 0.5f) ? 1.0f : 0.0f;
        out[(size_t)(b * Mp + i) * Ng + j] = cost * e;
    }
}

// ---------------------------------------------------------------------------
extern "C" void kernel_launch(void* const* d_in, const int* in_sizes, int n_in,
                              void* d_out, int out_size, void* d_ws, size_t ws_size,
                              hipStream_t stream) {
    (void)in_sizes; (void)n_in; (void)out_size; (void)ws_size;
    const float* pred  = (const float*)d_in[0];   // (2,40,24,2)
    const float* gt    = (const float*)d_in[1];   // (2,24,24,2)
    const float* vis   = (const float*)d_in[2];   // (2,24,24)
    const float* exist = (const float*)d_in[3];   // (2,24)

    float* ws      = (float*)d_ws;
    float* predRS  = ws;                                   // 2*40*64*2 = 10240
    float* gtRS    = predRS + (size_t)Bb * Mp * NRS * 2;   // 2*24*64*2 = 6144
    float* gtPM    = gtRS   + (size_t)Bb * Ng * NRS * 2;   // 2*24*24   = 1152
    float* maskSum = gtPM   + (size_t)Bb * Ng * NP;        // 128
    float* pmask   = maskSum + NSUM;                       // 2*40*9216 = 737280
    float* gmask   = pmask  + (size_t)Bb * Mp * HW;        // 2*24*9216 = 442368
    float* outp    = (float*)d_out;

    hipLaunchKernelGGL(k_resample, dim3(Bb * (Mp + Ng)), dim3(64), 0, stream,
                       pred, gt, vis, predRS, gtRS, gtPM, maskSum);
    hipLaunchKernelGGL(k_softmask, dim3(HW / 256, Bb * (Mp + Ng)), dim3(256), 0, stream,
                       pred, gt, gtPM, pmask, gmask, maskSum);
    hipLaunchKernelGGL(k_cost, dim3(Bb * Mp * Ng), dim3(256), 0, stream,
                       predRS, gtRS, pmask, gmask, maskSum, exist, outp);
}

// Round 3
// 99.715 us; speedup vs baseline: 1.6764x; 1.6764x over previous
//
#include <hip/hip_runtime.h>
#include <math.h>

#define Hh 72
#define Ww 128
#define HW (Hh*Ww)          // 9216 grid points
#define NP 24               // points per curve
#define NSEG (NP-1)
#define Mp 40               // pred curves
#define Ng 24               // gt curves
#define Bb 2                // batch
#define NRS 64
#define THICKc 0.03f
#define SHARPc 80.0f

// ---------------------------------------------------------------------------
// K1: prepare gt mask + arclength resample (both pred and gt) to NRS points.
// One block per curve, 64 threads (one per resample point).
// ---------------------------------------------------------------------------
__global__ __launch_bounds__(64) void k_resample(
    const float* __restrict__ pred,   // B*M*NP*2
    const float* __restrict__ gt,     // B*N*NP*2
    const float* __restrict__ vis,    // B*N*NP
    float* __restrict__ predRS,       // B*M*NRS*2
    float* __restrict__ gtRS,         // B*N*NRS*2
    float* __restrict__ gtPM)         // B*N*NP
{
    int blk = blockIdx.x;             // 0 .. B*(M+N)-1
    int b = blk / (Mp + Ng);
    int c = blk % (Mp + Ng);
    bool isPred = (c < Mp);
    int tid = threadIdx.x;

    __shared__ float qx[NP], qy[NP], pm[NP], cum[NP];
    __shared__ float s_total;

    const float* src = isPred ? pred + (size_t)(b * Mp + c) * NP * 2
                              : gt   + (size_t)(b * Ng + (c - Mp)) * NP * 2;
    if (tid < NP) {
        float2 v = ((const float2*)src)[tid];
        qx[tid] = v.x;
        qy[tid] = v.y;
        pm[tid] = isPred ? 1.0f
                         : ((vis[(b * Ng + (c - Mp)) * NP + tid] > 0.5f) ? 1.0f : 0.0f);
    }
    __syncthreads();
    if (tid == 0) {
        if (!isPred) {
            float s = 0.0f;
            for (int p = 0; p < NP; p++) s += pm[p];
            if (s < 2.0f)                       // fallback: fewer than 2 visible
                for (int p = 0; p < NP; p++) pm[p] = 1.0f;
        }
        float acc = 0.0f;
        cum[0] = 0.0f;
        for (int s = 0; s < NSEG; s++) {
            float dx = qx[s + 1] - qx[s], dy = qy[s + 1] - qy[s];
            float sl = sqrtf(dx * dx + dy * dy) * (pm[s] * pm[s + 1]);
            acc += sl;
            cum[s + 1] = acc;
        }
        s_total = acc;
    }
    __syncthreads();
    if (!isPred && tid < NP) gtPM[(b * Ng + (c - Mp)) * NP + tid] = pm[tid];

    float total = s_total;
    float t = ((float)tid / 63.0f) * total;
    // searchsorted(cum, t, side='right') - 1  == count(cum <= t) - 1
    int cnt = 0;
    for (int p = 0; p < NP; p++) cnt += (cum[p] <= t) ? 1 : 0;
    int idx = cnt - 1;
    idx = (idx < 0) ? 0 : ((idx > NP - 2) ? NP - 2 : idx);
    float lt = cum[idx], rt = cum[idx + 1];
    float alpha = (t - lt) / fmaxf(rt - lt, 1e-8f);
    float ox = qx[idx] + alpha * (qx[idx + 1] - qx[idx]);
    float oy = qy[idx] + alpha * (qy[idx + 1] - qy[idx]);
    if (total < 1e-8f) { ox = qx[0]; oy = qy[0]; }   // degenerate curve
    float* dst = isPred ? predRS + (size_t)(b * Mp + c) * NRS * 2
                        : gtRS   + (size_t)(b * Ng + (c - Mp)) * NRS * 2;
    dst[tid * 2 + 0] = ox;
    dst[tid * 2 + 1] = oy;
}

// ---------------------------------------------------------------------------
// K2: soft occupancy masks on the ORIGINAL 24-pt polylines.
// grid = (HW/256, B*(M+N)); block handles 256 grid points of one curve.
// Per-segment data (a, ab, 1/denom, valid) hoisted into LDS once per block.
// NO atomics (R1 post-mortem: 18k atomics on 8 cache lines cost ~45 us).
// ---------------------------------------------------------------------------
__global__ __launch_bounds__(256) void k_softmask(
    const float* __restrict__ pred,
    const float* __restrict__ gt,
    const float* __restrict__ gtPM,
    float* __restrict__ pmask,        // B*M*HW
    float* __restrict__ gmask)        // B*N*HW
{
    int c = blockIdx.y;               // 0 .. B*(M+N)-1
    int b = c / (Mp + Ng);
    int cc = c % (Mp + Ng);
    bool isPred = (cc < Mp);
    int g = blockIdx.x * blockDim.x + threadIdx.x;

    __shared__ float qx[NP], qy[NP], pm[NP];
    __shared__ float sax[NSEG], say[NSEG], sabx[NSEG], saby[NSEG], sinv[NSEG], svld[NSEG];
    if (threadIdx.x < NP) {
        const float* src = isPred ? pred + (size_t)(b * Mp + cc) * NP * 2
                                  : gt   + (size_t)(b * Ng + (cc - Mp)) * NP * 2;
        float2 v = ((const float2*)src)[threadIdx.x];
        qx[threadIdx.x] = v.x;
        qy[threadIdx.x] = v.y;
        pm[threadIdx.x] = isPred ? 1.0f : gtPM[(b * Ng + (cc - Mp)) * NP + threadIdx.x];
    }
    __syncthreads();
    if (threadIdx.x < NSEG) {
        int s = threadIdx.x;
        float ax = qx[s], ay = qy[s];
        float abx = qx[s + 1] - ax, aby = qy[s + 1] - ay;
        sax[s] = ax; say[s] = ay; sabx[s] = abx; saby[s] = aby;
        sinv[s] = 1.0f / fmaxf(abx * abx + aby * aby, 1e-8f);
        svld[s] = (pm[s] * pm[s + 1] > 0.5f) ? 1.0f : 0.0f;
    }
    __syncthreads();

    float gx = (float)(g & (Ww - 1)) * (1.0f / 127.0f);
    float gy = (float)(g >> 7) * (1.0f / 71.0f);

    float best2 = 1e30f;
    bool anyValid = false;
    for (int s = 0; s < NSEG; s++) {
        if (svld[s] > 0.5f) {                    // wave-uniform branch
            anyValid = true;
            float ax = sax[s], ay = say[s];
            float abx = sabx[s], aby = saby[s];
            float t = ((gx - ax) * abx + (gy - ay) * aby) * sinv[s];
            t = fminf(fmaxf(t, 0.0f), 1.0f);
            float dx = gx - (ax + t * abx), dy = gy - (ay + t * aby);
            best2 = fminf(best2, dx * dx + dy * dy);
        }
    }
    float mind;
    if (anyValid) {
        mind = sqrtf(best2);
    } else {
        float b2 = 1e30f;
        for (int p = 0; p < NP; p++) {
            if (pm[p] > 0.5f) {
                float dx = gx - qx[p], dy = gy - qy[p];
                b2 = fminf(b2, dx * dx + dy * dy);
            }
        }
        mind = sqrtf(b2);
    }
    float x = (THICKc - mind) * SHARPc;
    float mval = 1.0f / (1.0f + __expf(-x));
    if (isPred) pmask[(size_t)(b * Mp + cc) * HW + g] = mval;
    else        gmask[(size_t)(b * Ng + (cc - Mp)) * HW + g] = mval;
}

// ---------------------------------------------------------------------------
// K3: per-(b,i,j) pair cost. 256 threads stream both mask rows (float4),
// accumulating Smin, Sp, Sq in one pass; union = Sp + Sq - Smin (min+max
// == p+q identity) so no max stream and no cross-block accumulators.
// Wave 0 does Chamfer/tangent/curvature. One barrier total.
// ---------------------------------------------------------------------------
__global__ __launch_bounds__(256) void k_cost(
    const float* __restrict__ predRS,
    const float* __restrict__ gtRS,
    const float* __restrict__ pmask,
    const float* __restrict__ gmask,
    const float* __restrict__ gtExist,   // B*N
    float* __restrict__ out)             // B*M*N
{
    int pair = blockIdx.x;               // B*M*N
    int j = pair % Ng;
    int i = (pair / Ng) % Mp;
    int b = pair / (Ng * Mp);
    int tid = threadIdx.x;
    int lane = tid & 63, wid = tid >> 6;

    __shared__ float px[NRS], py[NRS], gxr[NRS], gyr[NRS];
    __shared__ float pmin[4], psp[4], psq[4];

    if (tid < NRS) {
        px[tid]  = predRS[((size_t)(b * Mp + i) * NRS + tid) * 2 + 0];
        py[tid]  = predRS[((size_t)(b * Mp + i) * NRS + tid) * 2 + 1];
        gxr[tid] = gtRS[((size_t)(b * Ng + j) * NRS + tid) * 2 + 0];
        gyr[tid] = gtRS[((size_t)(b * Ng + j) * NRS + tid) * 2 + 1];
    }
    __syncthreads();

    // ---- one-pass grid sums: min(p,q), p, q ----
    const float4* pm4 = (const float4*)(pmask + (size_t)(b * Mp + i) * HW);
    const float4* gm4 = (const float4*)(gmask + (size_t)(b * Ng + j) * HW);
    float smin = 0.0f, sp = 0.0f, sq = 0.0f;
    for (int g = tid; g < HW / 4; g += 256) {
        float4 p = pm4[g], q = gm4[g];
        smin += fminf(p.x, q.x) + fminf(p.y, q.y) + fminf(p.z, q.z) + fminf(p.w, q.w);
        sp   += p.x + p.y + p.z + p.w;
        sq   += q.x + q.y + q.z + q.w;
    }

    float symv = 0.0f, tanv = 0.0f, curvv = 0.0f;
    if (wid == 0) {
        // Chamfer: pred point lane -> gt polyline
        float p0x = px[lane], p0y = py[lane];
        float bst = 1e30f;
        for (int s = 0; s < NRS - 1; s++) {
            float ax = gxr[s], ay = gyr[s];
            float abx = gxr[s + 1] - ax, aby = gyr[s + 1] - ay;
            float denom = fmaxf(abx * abx + aby * aby, 1e-8f);
            float t = ((p0x - ax) * abx + (p0y - ay) * aby) / denom;
            t = fminf(fmaxf(t, 0.0f), 1.0f);
            float dx = p0x - (ax + t * abx), dy = p0y - (ay + t * aby);
            bst = fminf(bst, dx * dx + dy * dy);
        }
        float dpg = sqrtf(bst);
        // gt point lane -> pred polyline
        float q0x = gxr[lane], q0y = gyr[lane];
        bst = 1e30f;
        for (int s = 0; s < NRS - 1; s++) {
            float ax = px[s], ay = py[s];
            float abx = px[s + 1] - ax, aby = py[s + 1] - ay;
            float denom = fmaxf(abx * abx + aby * aby, 1e-8f);
            float t = ((q0x - ax) * abx + (q0y - ay) * aby) / denom;
            t = fminf(fmaxf(t, 0.0f), 1.0f);
            float dx = q0x - (ax + t * abx), dy = q0y - (ay + t * aby);
            bst = fminf(bst, dx * dx + dy * dy);
        }
        float dgp = sqrtf(bst);
        symv = 0.5f * (dpg + dgp);

        // tangent alignment
        int kp = (lane == NRS - 1) ? NRS - 1 : lane + 1;
        int km = (lane == 0) ? 0 : lane - 1;
        float tx = px[kp] - px[km], ty = py[kp] - py[km];
        float nrm = fmaxf(sqrtf(tx * tx + ty * ty), 1e-8f);
        tx /= nrm; ty /= nrm;
        float gtx = gxr[kp] - gxr[km], gty = gyr[kp] - gyr[km];
        float nrm2 = fmaxf(sqrtf(gtx * gtx + gty * gty), 1e-8f);
        gtx /= nrm2; gty /= nrm2;
        tanv = fabsf(tx * gtx + ty * gty);

        // curvature (second differences), lanes 0..61
        if (lane < NRS - 2) {
            float psx = px[lane + 2] - 2.0f * px[lane + 1] + px[lane];
            float psy = py[lane + 2] - 2.0f * py[lane + 1] + py[lane];
            float gsx = gxr[lane + 2] - 2.0f * gxr[lane + 1] + gxr[lane];
            float gsy = gyr[lane + 2] - 2.0f * gyr[lane + 1] + gyr[lane];
            float d1 = fabsf(psx - gsx);
            float d2 = fabsf(psy - gsy);
            float c1 = (d1 < 1.0f) ? 0.5f * d1 * d1 : d1 - 0.5f;
            float c2 = (d2 < 1.0f) ? 0.5f * d2 * d2 : d2 - 0.5f;
            curvv = c1 + c2;
        }
    }

    // per-wave shuffle reduce (all 4 waves); wave 0 also reduces curve terms
    for (int off = 32; off > 0; off >>= 1) {
        smin += __shfl_down(smin, off);
        sp   += __shfl_down(sp, off);
        sq   += __shfl_down(sq, off);
    }
    if (lane == 0) { pmin[wid] = smin; psp[wid] = sp; psq[wid] = sq; }
    if (wid == 0) {
        for (int off = 32; off > 0; off >>= 1) {
            symv  += __shfl_down(symv,  off);
            tanv  += __shfl_down(tanv,  off);
            curvv += __shfl_down(curvv, off);
        }
    }
    __syncthreads();

    if (tid == 0) {
        float Smin = pmin[0] + pmin[1] + pmin[2] + pmin[3];
        float Sp   = psp[0] + psp[1] + psp[2] + psp[3];
        float Sq   = psq[0] + psq[1] + psq[2] + psq[3];
        float Smax = Sp + Sq - Smin;          // min+max == p+q
        float overlap = 1.0f - Smin / (Smax + 1e-8f);
        float sym  = symv * (1.0f / 64.0f);
        float tanl = 1.0f - tanv * (1.0f / 64.0f);
        float curv = curvv * (1.0f / 124.0f);
        float cost = 5.0f * sym + 1.0f * tanl + 0.5f * curv + 2.0f * overlap;
        float e = (gtExist[b * Ng + j] > 0.5f) ? 1.0f : 0.0f;
        out[(size_t)(b * Mp + i) * Ng + j] = cost * e;
    }
}

// ---------------------------------------------------------------------------
extern "C" void kernel_launch(void* const* d_in, const int* in_sizes, int n_in,
                              void* d_out, int out_size, void* d_ws, size_t ws_size,
                              hipStream_t stream) {
    (void)in_sizes; (void)n_in; (void)out_size; (void)ws_size;
    const float* pred  = (const float*)d_in[0];   // (2,40,24,2)
    const float* gt    = (const float*)d_in[1];   // (2,24,24,2)
    const float* vis   = (const float*)d_in[2];   // (2,24,24)
    const float* exist = (const float*)d_in[3];   // (2,24)

    float* ws      = (float*)d_ws;
    float* predRS  = ws;                                   // 2*40*64*2 = 10240
    float* gtRS    = predRS + (size_t)Bb * Mp * NRS * 2;   // 2*24*64*2 = 6144
    float* gtPM    = gtRS   + (size_t)Bb * Ng * NRS * 2;   // 2*24*24   = 1152
    float* pmask   = gtPM   + (size_t)Bb * Ng * NP;        // 2*40*9216 = 737280
    float* gmask   = pmask  + (size_t)Bb * Mp * HW;        // 2*24*9216 = 442368
    float* outp    = (float*)d_out;

    hipLaunchKernelGGL(k_resample, dim3(Bb * (Mp + Ng)), dim3(64), 0, stream,
                       pred, gt, vis, predRS, gtRS, gtPM);
    hipLaunchKernelGGL(k_softmask, dim3(HW / 256, Bb * (Mp + Ng)), dim3(256), 0, stream,
                       pred, gt, gtPM, pmask, gmask);
    hipLaunchKernelGGL(k_cost, dim3(Bb * Mp * Ng), dim3(256), 0, stream,
                       predRS, gtRS, pmask, gmask, exist, outp);
}